// Round 1
// baseline (381.441 us; speedup 1.0000x reference)
//
#include <hip/hip_runtime.h>

#define BATCH 64
#define TLEN  512
#define HDIM  768
#define LTAGS 9

// ---------------------------------------------------------------------------
// Kernel A: logits[b,t,l] = sum_h hidden[b,t,h] * W[l,h] + b[l], fp64 accum.
// One wave per row (768 floats = 3 x (64 lanes x float4)). W cached in LDS.
// ---------------------------------------------------------------------------
__global__ __launch_bounds__(256) void logits_kernel(
    const float* __restrict__ hidden, const float* __restrict__ W,
    const float* __restrict__ bvec, double* __restrict__ logitsD)
{
    __shared__ float sW[LTAGS * HDIM];   // 27648 B
    __shared__ float sb[LTAGS];
    const int tid = threadIdx.x;
    for (int i = tid; i < LTAGS * HDIM; i += 256) sW[i] = W[i];
    if (tid < LTAGS) sb[tid] = bvec[tid];
    __syncthreads();

    const int lane   = tid & 63;
    const int waveId = tid >> 6;
    const int nWaves = gridDim.x * 4;

    for (int r = blockIdx.x * 4 + waveId; r < BATCH * TLEN; r += nWaves) {
        const float4* hrow = (const float4*)(hidden + (size_t)r * HDIM);
        double acc[LTAGS];
        #pragma unroll
        for (int l = 0; l < LTAGS; ++l) acc[l] = 0.0;
        #pragma unroll
        for (int c = 0; c < 3; ++c) {
            float4 h = hrow[c * 64 + lane];
            #pragma unroll
            for (int l = 0; l < LTAGS; ++l) {
                const float4 w = *(const float4*)&sW[l * HDIM + c * 256 + lane * 4];
                double a = acc[l];
                a = fma((double)h.x, (double)w.x, a);
                a = fma((double)h.y, (double)w.y, a);
                a = fma((double)h.z, (double)w.z, a);
                a = fma((double)h.w, (double)w.w, a);
                acc[l] = a;
            }
        }
        #pragma unroll
        for (int l = 0; l < LTAGS; ++l) {
            double v = acc[l];
            #pragma unroll
            for (int off = 32; off > 0; off >>= 1) v += __shfl_down(v, off);
            if (lane == 0) logitsD[(size_t)r * LTAGS + l] = v + (double)sb[l];
        }
    }
}

// ---------------------------------------------------------------------------
// Kernel B: one block (128 thr = 2 waves) per batch.
//   wave 0: CRF alpha recursion (fp32, exp-trick) -> denominator
//   wave 1: Viterbi forward (fp64) + backtrace -> predictions
//   both:   numerator (emit+trans scores, fp64), computed t-parallel upfront
// ---------------------------------------------------------------------------
__global__ __launch_bounds__(128) void crf_kernel(
    const float* __restrict__ trans, const int* __restrict__ labels,
    const int* __restrict__ att, const double* __restrict__ logitsD,
    double* __restrict__ wsLoss, float* __restrict__ out)
{
    __shared__ double sLog[TLEN * LTAGS];        // 36864 B
    __shared__ int    sBP[(TLEN - 1) * LTAGS];   // 18396 B
    __shared__ unsigned char sMk[TLEN];          // 512 B
    __shared__ double sRed[2];
    __shared__ double sNum, sDen;

    const int b    = blockIdx.x;
    const int tid  = threadIdx.x;
    const int lane = tid & 63;
    const int wave = tid >> 6;

    // ---- preload this batch's fp64 logits into LDS (coalesced) ----
    const double* gL = logitsD + (size_t)b * TLEN * LTAGS;
    for (int i = tid; i < TLEN * LTAGS; i += 128) sLog[i] = gL[i];

    // ---- mask + per-t tag bookkeeping ----
    const int* lab = labels + b * TLEN;
    const int* am  = att + b * TLEN;
    int  myTag[4];
    bool myMk[4];
    #pragma unroll
    for (int k = 0; k < 4; ++k) {
        int t = k * 128 + tid;
        int lv = lab[t], av = am[t];
        bool mk = (av != 0) && (lv != -100);
        myMk[k]  = mk;
        myTag[k] = (lv == -100) ? 0 : lv;
        sMk[t]   = mk ? 1 : 0;
    }
    __syncthreads();

    // ---- numerator = emit_score + trans_score (fp64), t-parallel ----
    double part = 0.0;
    #pragma unroll
    for (int k = 0; k < 4; ++k) {
        int t = k * 128 + tid;
        if (myMk[k]) part += sLog[t * LTAGS + myTag[k]];
        if (t < TLEN - 1) {
            int lv2 = lab[t + 1], av2 = am[t + 1];
            bool mk2 = (av2 != 0) && (lv2 != -100);
            int  tg2 = (lv2 == -100) ? 0 : lv2;
            if (mk2) part += (double)trans[myTag[k] * LTAGS + tg2];
        }
    }
    #pragma unroll
    for (int off = 32; off > 0; off >>= 1) part += __shfl_down(part, off);
    if (lane == 0) sRed[wave] = part;
    __syncthreads();
    if (tid == 0) sNum = sRed[0] + sRed[1];
    __syncthreads();

    const int jj = (lane < LTAGS) ? lane : (LTAGS - 1);

    if (wave == 0) {
        // ================= alpha recursion (fp32) =================
        // new_j = m + logit_j + log( sum_i exp(alpha_i - m) * e^{trans_ij} )
        float Ecol[LTAGS];
        #pragma unroll
        for (int i = 0; i < LTAGS; ++i) Ecol[i] = expf(trans[i * LTAGS + jj]);
        float alpha = (float)sLog[jj];
        float lf = (float)sLog[1 * LTAGS + jj];
        unsigned char mk = sMk[1];
        for (int t = 1; t < TLEN; ++t) {
            float lfN = 0.f; unsigned char mkN = 0;
            if (t + 1 < TLEN) {                       // prefetch next step
                lfN = (float)sLog[(t + 1) * LTAGS + jj];
                mkN = sMk[t + 1];
            }
            float m = __shfl(alpha, 0);
            float p = __expf(alpha - m);
            float g0 = __shfl(p, 0), g1 = __shfl(p, 1), g2 = __shfl(p, 2);
            float g3 = __shfl(p, 3), g4 = __shfl(p, 4), g5 = __shfl(p, 5);
            float g6 = __shfl(p, 6), g7 = __shfl(p, 7), g8 = __shfl(p, 8);
            float s = ((g0 * Ecol[0] + g1 * Ecol[1]) + (g2 * Ecol[2] + g3 * Ecol[3]))
                    + ((g4 * Ecol[4] + g5 * Ecol[5]) + (g6 * Ecol[6] + g7 * Ecol[7]))
                    + g8 * Ecol[8];
            float na = m + lf + __logf(s);
            alpha = mk ? na : alpha;
            lf = lfN; mk = mkN;
        }
        // denominator = logsumexp(alpha) over 9 tags
        float a[LTAGS];
        #pragma unroll
        for (int i = 0; i < LTAGS; ++i) a[i] = __shfl(alpha, i);
        if (lane == 0) {
            float mm = a[0];
            #pragma unroll
            for (int i = 1; i < LTAGS; ++i) mm = fmaxf(mm, a[i]);
            float ss = 0.f;
            #pragma unroll
            for (int i = 0; i < LTAGS; ++i) ss += expf(a[i] - mm);
            sDen = (double)(mm + logf(ss));
        }
    } else {
        // ================= Viterbi forward (fp64) =================
        double Tcol[LTAGS];
        #pragma unroll
        for (int i = 0; i < LTAGS; ++i) Tcol[i] = (double)trans[i * LTAGS + jj];
        double vs = sLog[jj];
        double lg = sLog[1 * LTAGS + jj];
        unsigned char mk = sMk[1];
        for (int t = 1; t < TLEN; ++t) {
            double lgN = 0.0; unsigned char mkN = 0;
            if (t + 1 < TLEN) {                       // prefetch next step
                lgN = sLog[(t + 1) * LTAGS + jj];
                mkN = sMk[t + 1];
            }
            double g0 = __shfl(vs, 0), g1 = __shfl(vs, 1), g2 = __shfl(vs, 2);
            double g3 = __shfl(vs, 3), g4 = __shfl(vs, 4), g5 = __shfl(vs, 5);
            double g6 = __shfl(vs, 6), g7 = __shfl(vs, 7), g8 = __shfl(vs, 8);
            double c0 = g0 + Tcol[0], c1 = g1 + Tcol[1], c2 = g2 + Tcol[2];
            double c3 = g3 + Tcol[3], c4 = g4 + Tcol[4], c5 = g5 + Tcol[5];
            double c6 = g6 + Tcol[6], c7 = g7 + Tcol[7], c8 = g8 + Tcol[8];
            // tournament argmax; ties -> lowest index (matches jnp.argmax)
            double v01 = c0; int i01 = 0; if (c1 > v01) { v01 = c1; i01 = 1; }
            double v23 = c2; int i23 = 2; if (c3 > v23) { v23 = c3; i23 = 3; }
            double v45 = c4; int i45 = 4; if (c5 > v45) { v45 = c5; i45 = 5; }
            double v67 = c6; int i67 = 6; if (c7 > v67) { v67 = c7; i67 = 7; }
            double vA = v01; int iA = i01; if (v23 > vA) { vA = v23; iA = i23; }
            double vB = v45; int iB = i45; if (v67 > vB) { vB = v67; iB = i67; }
            if (vB > vA) { vA = vB; iA = iB; }
            if (c8 > vA) { vA = c8; iA = 8; }
            double nv = vA + lg;
            int bp = mk ? iA : jj;
            if (mk) vs = nv;
            if (lane < LTAGS) sBP[(t - 1) * LTAGS + lane] = bp;
            lg = lgN; mk = mkN;
        }
        // last_tag + backtrace + predictions
        double vv[LTAGS];
        #pragma unroll
        for (int i = 0; i < LTAGS; ++i) vv[i] = __shfl(vs, i);
        if (lane == 0) {
            int best = 0; double bv = vv[0];
            #pragma unroll
            for (int i = 1; i < LTAGS; ++i) if (vv[i] > bv) { bv = vv[i]; best = i; }
            int cur = best;                         // tag at time T-1
            float* po = out + 1 + b * TLEN;
            for (int u = TLEN - 2; u >= 0; --u) {
                int tg = sBP[u * LTAGS + cur];      // tag at time u
                po[u + 1] = sMk[u] ? (float)tg : -100.0f;
                cur = tg;
            }
            po[0] = -100.0f;
        }
    }
    __syncthreads();
    if (tid == 0) wsLoss[b] = sDen - sNum;          // loss contribution (positive)
}

// ---------------------------------------------------------------------------
// Kernel C: loss = sum_b (den_b - num_b)
// ---------------------------------------------------------------------------
__global__ __launch_bounds__(64) void loss_kernel(
    const double* __restrict__ wsLoss, float* __restrict__ out)
{
    double v = wsLoss[threadIdx.x];
    #pragma unroll
    for (int off = 32; off > 0; off >>= 1) v += __shfl_down(v, off);
    if (threadIdx.x == 0) out[0] = (float)v;
}

extern "C" void kernel_launch(void* const* d_in, const int* in_sizes, int n_in,
                              void* d_out, int out_size, void* d_ws, size_t ws_size,
                              hipStream_t stream)
{
    const float* hidden = (const float*)d_in[0];   // (64,512,768) f32
    const float* W      = (const float*)d_in[1];   // (9,768) f32
    const float* bvec   = (const float*)d_in[2];   // (9,) f32
    const float* trans  = (const float*)d_in[3];   // (9,9) f32
    const int*   labels = (const int*)d_in[4];     // (64,512) i32
    const int*   att    = (const int*)d_in[5];     // (64,512) i32
    float* out = (float*)d_out;                    // [loss(1)] ++ [preds(64*512)]

    double* logitsD = (double*)d_ws;                                   // 2359296 B
    double* wsLoss  = (double*)((char*)d_ws + (size_t)BATCH * TLEN * LTAGS * sizeof(double));

    logits_kernel<<<1024, 256, 0, stream>>>(hidden, W, bvec, logitsD);
    crf_kernel<<<BATCH, 128, 0, stream>>>(trans, labels, att, logitsD, wsLoss, out);
    loss_kernel<<<1, 64, 0, stream>>>(wsLoss, out);
}

// Round 2
// 262.825 us; speedup vs baseline: 1.4513x; 1.4513x over previous
//
#include <hip/hip_runtime.h>

#define BATCH 64
#define TLEN  512
#define HDIM  768
#define LTAGS 9

// Workspace layout (bytes)
#define WS_LOGD 0                        // f64 [32768][9]   = 2359296
#define WS_LOGF 2359296                  // f32 [32768][9]   = 1179648
#define WS_VM   3538944                  // f64 [64][64][9][9] = 2654208  (viterbi chunk mats)
#define WS_AM   6193152                  // f32 [64][32][9][9] = 663552   (alpha chunk mats)
#define WS_NUM  6856704                  // f64 [64]
#define WS_LOSS 6857216                  // f64 [64]

// ---------------------------------------------------------------------------
// Kernel A: logits = hidden @ W^T + b.  f32 dot4 segments accumulated in f64
// (error ~1e-7 -- far below Viterbi decision margins).  8 lanes per row,
// 2 rows per lane (row-pair blocking); W in LDS f32, broadcast across groups.
// Writes f64 and f32 copies of logits.
// ---------------------------------------------------------------------------
__global__ __launch_bounds__(256) void logits_kernel(
    const float* __restrict__ hidden, const float* __restrict__ W,
    const float* __restrict__ bvec, double* __restrict__ logitsD,
    float* __restrict__ logitsF)
{
    __shared__ float sW[LTAGS * HDIM];   // 27648 B
    __shared__ float sb[LTAGS];
    const int tid = threadIdx.x;
    for (int i = tid; i < LTAGS * HDIM; i += 256) sW[i] = W[i];
    if (tid < LTAGS) sb[tid] = bvec[tid];
    __syncthreads();

    const int lane = tid & 63;
    const int wave = tid >> 6;
    const int sub  = lane & 7;    // h-slice owner within 8-lane group
    const int rg   = lane >> 3;   // row-group 0..7

    // block handles 64 rows: wave handles 16 (rg and rg+8)
    const int rowBase = blockIdx.x * 64 + wave * 16;
    const int r0 = rowBase + rg;
    const int r1 = rowBase + rg + 8;
    const float* h0p = hidden + (size_t)r0 * HDIM;
    const float* h1p = hidden + (size_t)r1 * HDIM;

    double acc0[LTAGS], acc1[LTAGS];
    #pragma unroll
    for (int l = 0; l < LTAGS; ++l) { acc0[l] = 0.0; acc1[l] = 0.0; }

    #pragma unroll 2
    for (int i = 0; i < 24; ++i) {
        const int off = i * 32 + sub * 4;
        const float4 h0 = *(const float4*)(h0p + off);
        const float4 h1 = *(const float4*)(h1p + off);
        #pragma unroll
        for (int l = 0; l < LTAGS; ++l) {
            const float4 w = *(const float4*)&sW[l * HDIM + off];
            float d0 = h0.x * w.x;
            d0 = fmaf(h0.y, w.y, d0); d0 = fmaf(h0.z, w.z, d0); d0 = fmaf(h0.w, w.w, d0);
            float d1 = h1.x * w.x;
            d1 = fmaf(h1.y, w.y, d1); d1 = fmaf(h1.z, w.z, d1); d1 = fmaf(h1.w, w.w, d1);
            acc0[l] += (double)d0;
            acc1[l] += (double)d1;
        }
    }
    // reduce across 8-lane group (3 levels)
    #pragma unroll
    for (int l = 0; l < LTAGS; ++l) {
        double v0 = acc0[l], v1 = acc1[l];
        #pragma unroll
        for (int off = 4; off > 0; off >>= 1) {
            v0 += __shfl_down(v0, off);
            v1 += __shfl_down(v1, off);
        }
        acc0[l] = v0; acc1[l] = v1;
    }
    if (sub == 0) {
        #pragma unroll
        for (int l = 0; l < LTAGS; ++l) {
            double v0 = acc0[l] + (double)sb[l];
            double v1 = acc1[l] + (double)sb[l];
            logitsD[(size_t)r0 * LTAGS + l] = v0;
            logitsD[(size_t)r1 * LTAGS + l] = v1;
            logitsF[(size_t)r0 * LTAGS + l] = (float)v0;
            logitsF[(size_t)r1 * LTAGS + l] = (float)v1;
        }
    }
}

// ---------------------------------------------------------------------------
// Kernel B1 (crf1): per-batch block, 576 threads.
//  - numerator (f64) as before
//  - Viterbi chunk matrices: 64 chunks x 8 steps, max-plus, f64 -> wsVM
//  - Alpha  chunk matrices: 32 chunks x 16 steps, log-plus, f32 -> wsAM
// ---------------------------------------------------------------------------
__global__ __launch_bounds__(576) void crf1_kernel(
    const float* __restrict__ trans, const int* __restrict__ labels,
    const int* __restrict__ att, const double* __restrict__ logitsD,
    const float* __restrict__ logitsF,
    double* __restrict__ wsVM, float* __restrict__ wsAM,
    double* __restrict__ wsNum)
{
    __shared__ float  sLogF[513 * LTAGS];  // 18468 B (row 512 = zero pad)
    __shared__ double sT64[81];
    __shared__ float  sE32[81];            // exp(T)
    __shared__ unsigned char sMk[513];
    __shared__ double sRedN[9];

    const int b = blockIdx.x, tid = threadIdx.x;

    const float* gF = logitsF + (size_t)b * TLEN * LTAGS;
    for (int i = tid; i < TLEN * LTAGS; i += 576) sLogF[i] = gF[i];
    if (tid < LTAGS) sLogF[TLEN * LTAGS + tid] = 0.f;
    if (tid < 81) { float tv = trans[tid]; sT64[tid] = (double)tv; sE32[tid] = __expf(tv); }

    const int* lab = labels + b * TLEN;
    const int* am  = att + b * TLEN;
    if (tid < TLEN) {
        int lv = lab[tid], av = am[tid];
        sMk[tid] = (av != 0 && lv != -100) ? 1 : 0;
    }
    if (tid == 0) sMk[TLEN] = 0;
    __syncthreads();

    // ---- numerator ----
    double part = 0.0;
    if (tid < TLEN) {
        const int t = tid;
        int lv = lab[t];
        int tg = (lv == -100) ? 0 : lv;
        if (sMk[t]) part += logitsD[((size_t)b * TLEN + t) * LTAGS + tg];
        if (t < TLEN - 1 && sMk[t + 1]) {
            int lv2 = lab[t + 1];
            int tg2 = (lv2 == -100) ? 0 : lv2;
            part += (double)trans[tg * LTAGS + tg2];
        }
    }
    #pragma unroll
    for (int off = 32; off > 0; off >>= 1) part += __shfl_down(part, off);
    if ((tid & 63) == 0) sRedN[tid >> 6] = part;
    __syncthreads();
    if (tid == 0) {
        double s = 0.0;
        for (int w = 0; w < 8; ++w) s += sRedN[w];
        wsNum[b] = s;
    }

    // ---- Viterbi chunk matrices (f64, max-plus): all 576 threads ----
    {
        const int c = tid / 9, i = tid - 9 * c;   // chunk 0..63, row 0..8
        double M[LTAGS];
        #pragma unroll
        for (int j = 0; j < LTAGS; ++j) M[j] = (i == j) ? 0.0 : -1e300;

        const double* lrow = logitsD + ((size_t)b * TLEN + (c * 8 + 1)) * LTAGS;
        double lg[LTAGS], lgN[LTAGS];
        #pragma unroll
        for (int j = 0; j < LTAGS; ++j) lg[j] = lrow[j];

        for (int s = 0; s < 8; ++s) {
            const int t = c * 8 + 1 + s;
            if (s < 7) {
                const double* ln = lrow + (s + 1) * LTAGS;
                #pragma unroll
                for (int j = 0; j < LTAGS; ++j) lgN[j] = ln[j];
            }
            const bool mk = (sMk[t] != 0);
            double nw[LTAGS];
            #pragma unroll
            for (int j = 0; j < LTAGS; ++j) {
                double bst = M[0] + sT64[j];
                #pragma unroll
                for (int k = 1; k < LTAGS; ++k) {
                    double cnd = M[k] + sT64[k * LTAGS + j];
                    bst = fmax(bst, cnd);
                }
                nw[j] = bst + lg[j];
            }
            #pragma unroll
            for (int j = 0; j < LTAGS; ++j) M[j] = mk ? nw[j] : M[j];
            #pragma unroll
            for (int j = 0; j < LTAGS; ++j) lg[j] = lgN[j];
        }
        double* dst = wsVM + (((size_t)b * 64 + c) * LTAGS + i) * LTAGS;
        #pragma unroll
        for (int j = 0; j < LTAGS; ++j) dst[j] = M[j];
    }

    // ---- Alpha chunk matrices (f32, log-plus): threads 0..287 ----
    if (tid < 288) {
        const int c = tid / 9, i = tid - 9 * c;   // chunk 0..31, row 0..8
        float M[LTAGS];
        #pragma unroll
        for (int j = 0; j < LTAGS; ++j) M[j] = (i == j) ? 0.f : -1e30f;

        for (int s = 0; s < 16; ++s) {
            const int t = c * 16 + 1 + s;
            const bool mk = (sMk[t] != 0);
            float m = M[0];
            #pragma unroll
            for (int k = 1; k < LTAGS; ++k) m = fmaxf(m, M[k]);
            float P[LTAGS];
            #pragma unroll
            for (int k = 0; k < LTAGS; ++k) P[k] = __expf(M[k] - m);
            float nw[LTAGS];
            #pragma unroll
            for (int j = 0; j < LTAGS; ++j) {
                float sacc = P[0] * sE32[j];
                #pragma unroll
                for (int k = 1; k < LTAGS; ++k) sacc = fmaf(P[k], sE32[k * LTAGS + j], sacc);
                nw[j] = m + __logf(sacc) + sLogF[t * LTAGS + j];
            }
            #pragma unroll
            for (int j = 0; j < LTAGS; ++j) M[j] = mk ? nw[j] : M[j];
        }
        float* dst = wsAM + (((size_t)b * 32 + c) * LTAGS + i) * LTAGS;
        #pragma unroll
        for (int j = 0; j < LTAGS; ++j) dst[j] = M[j];
    }
}

// ---------------------------------------------------------------------------
// Kernel B2 (crf2): per-batch block, 128 threads.
//  wave0: serial max-plus scan over 64 chunk matrices (chunk-start vectors,
//         last_tag), then chunk-parallel replay emitting backpointers,
//         map-composition backtrace, predictions.
//  wave1: serial log-plus scan over 32 alpha chunk matrices -> denominator.
// ---------------------------------------------------------------------------
__global__ __launch_bounds__(128) void crf2_kernel(
    const float* __restrict__ trans, const int* __restrict__ labels,
    const int* __restrict__ att, const double* __restrict__ logitsD,
    const double* __restrict__ wsVM, const float* __restrict__ wsAM,
    const double* __restrict__ wsNum, double* __restrict__ wsLoss,
    float* __restrict__ out)
{
    __shared__ double sVstart[65 * LTAGS];            // 4680 B
    __shared__ unsigned long long sBPp[513];          // 4104 B (packed bp nibbles)
    __shared__ unsigned long long sFmap[64];          // chunk backtrace maps
    __shared__ int sTagB[65];                         // tags at chunk boundaries (t=8c)
    __shared__ double sT64[81];
    __shared__ unsigned char sMk[513];
    __shared__ double sDen;
    __shared__ int sLast;

    const int b = blockIdx.x, tid = threadIdx.x;
    const int wave = tid >> 6, lane = tid & 63;
    const unsigned long long IDMAP = 0x876543210ull;

    const int* lab = labels + b * TLEN;
    const int* am  = att + b * TLEN;
    for (int t = tid; t < TLEN; t += 128) {
        int lv = lab[t], av = am[t];
        sMk[t] = (av != 0 && lv != -100) ? 1 : 0;
    }
    if (tid == 0) sMk[TLEN] = 0;
    if (tid < 81) sT64[tid] = (double)trans[tid];
    __syncthreads();

    if (wave == 0) {
        // ---- Viterbi V2: serial scan over 64 chunk matrices ----
        const int j = (lane < LTAGS) ? lane : (LTAGS - 1);
        double v = logitsD[(size_t)b * TLEN * LTAGS + j];   // alpha0 = logits[:,0]
        const double* vmB = wsVM + (size_t)b * 64 * 81;
        double Mc[LTAGS], Mn[LTAGS];
        #pragma unroll
        for (int i = 0; i < LTAGS; ++i) Mc[i] = vmB[i * LTAGS + j];
        for (int c = 0; c < 64; ++c) {
            if (c < 63) {
                const double* p = vmB + (c + 1) * 81;
                #pragma unroll
                for (int i = 0; i < LTAGS; ++i) Mn[i] = p[i * LTAGS + j];
            }
            if (lane < LTAGS) sVstart[c * LTAGS + j] = v;
            double g[LTAGS];
            #pragma unroll
            for (int i = 0; i < LTAGS; ++i) g[i] = __shfl(v, i);
            double bst = g[0] + Mc[0];
            #pragma unroll
            for (int i = 1; i < LTAGS; ++i) bst = fmax(bst, g[i] + Mc[i]);
            v = bst;
            if (c < 63) {
                #pragma unroll
                for (int i = 0; i < LTAGS; ++i) Mc[i] = Mn[i];
            }
        }
        if (lane < LTAGS) sVstart[64 * LTAGS + j] = v;
        double g[LTAGS];
        #pragma unroll
        for (int i = 0; i < LTAGS; ++i) g[i] = __shfl(v, i);
        if (lane == 0) {
            int bi = 0; double bv = g[0];
            #pragma unroll
            for (int i = 1; i < LTAGS; ++i) if (g[i] > bv) { bv = g[i]; bi = i; }
            sLast = bi;
        }
    } else {
        // ---- Alpha V2: serial log-plus scan over 32 chunk matrices ----
        const int j = (lane < LTAGS) ? lane : (LTAGS - 1);
        float v = (float)logitsD[(size_t)b * TLEN * LTAGS + j];
        const float* amB = wsAM + (size_t)b * 32 * 81;
        float Mc[LTAGS], Mn[LTAGS];
        #pragma unroll
        for (int i = 0; i < LTAGS; ++i) Mc[i] = amB[i * LTAGS + j];
        for (int c = 0; c < 32; ++c) {
            if (c < 31) {
                const float* p = amB + (c + 1) * 81;
                #pragma unroll
                for (int i = 0; i < LTAGS; ++i) Mn[i] = p[i * LTAGS + j];
            }
            float g[LTAGS];
            #pragma unroll
            for (int i = 0; i < LTAGS; ++i) g[i] = __shfl(v, i);
            float a[LTAGS];
            #pragma unroll
            for (int i = 0; i < LTAGS; ++i) a[i] = g[i] + Mc[i];
            float m = a[0];
            #pragma unroll
            for (int i = 1; i < LTAGS; ++i) m = fmaxf(m, a[i]);
            float sacc = 0.f;
            #pragma unroll
            for (int i = 0; i < LTAGS; ++i) sacc += __expf(a[i] - m);
            v = m + __logf(sacc);
            if (c < 31) {
                #pragma unroll
                for (int i = 0; i < LTAGS; ++i) Mc[i] = Mn[i];
            }
        }
        float g[LTAGS];
        #pragma unroll
        for (int i = 0; i < LTAGS; ++i) g[i] = __shfl(v, i);
        if (lane == 0) {
            float m = g[0];
            #pragma unroll
            for (int i = 1; i < LTAGS; ++i) m = fmaxf(m, g[i]);
            float sacc = 0.f;
            #pragma unroll
            for (int i = 0; i < LTAGS; ++i) sacc += __expf(g[i] - m);
            sDen = (double)(m + __logf(sacc));
        }
    }
    __syncthreads();

    // ---- V3: chunk-parallel replay + backpointers + chunk maps (wave 0) ----
    if (tid < 64) {
        const int c = tid;
        double v[LTAGS];
        #pragma unroll
        for (int j = 0; j < LTAGS; ++j) v[j] = sVstart[c * LTAGS + j];
        const double* lrow = logitsD + ((size_t)b * TLEN + (c * 8 + 1)) * LTAGS;
        double lg[LTAGS], lgN[LTAGS];
        #pragma unroll
        for (int j = 0; j < LTAGS; ++j) lg[j] = lrow[j];

        for (int s = 0; s < 8; ++s) {
            const int t = c * 8 + 1 + s;
            if (s < 7) {
                const double* ln = lrow + (s + 1) * LTAGS;
                #pragma unroll
                for (int j = 0; j < LTAGS; ++j) lgN[j] = ln[j];
            }
            const bool mk = (sMk[t] != 0);
            unsigned long long pk = 0;
            double nv[LTAGS];
            #pragma unroll
            for (int j = 0; j < LTAGS; ++j) {
                double bst = v[0] + sT64[j];
                int bi = 0;
                #pragma unroll
                for (int k = 1; k < LTAGS; ++k) {
                    double cnd = v[k] + sT64[k * LTAGS + j];
                    bool gt = cnd > bst;          // strict > : ties keep lowest i
                    bst = gt ? cnd : bst;
                    bi  = gt ? k : bi;
                }
                nv[j] = bst + lg[j];
                pk |= ((unsigned long long)bi) << (4 * j);
            }
            pk = mk ? pk : IDMAP;
            sBPp[t] = pk;
            #pragma unroll
            for (int j = 0; j < LTAGS; ++j) v[j] = mk ? nv[j] : v[j];
            #pragma unroll
            for (int j = 0; j < LTAGS; ++j) lg[j] = lgN[j];
        }
        // compose chunk backtrace map: F_c = f_{8c+1} o ... o f_{8c+8}
        unsigned long long G = IDMAP;
        for (int s = 7; s >= 0; --s) {
            const unsigned long long bp = sBPp[c * 8 + 1 + s];
            unsigned long long ng = 0;
            #pragma unroll
            for (int j = 0; j < LTAGS; ++j) {
                int gj = (int)((G >> (4 * j)) & 15);
                int f  = (int)((bp >> (4 * gj)) & 15);
                ng |= ((unsigned long long)f) << (4 * j);
            }
            G = ng;
        }
        sFmap[c] = G;
    }
    __syncthreads();

    // ---- serial boundary backtrace over 64 chunk maps ----
    if (tid == 0) {
        int cur = sLast;
        sTagB[64] = cur;
        for (int c = 63; c >= 0; --c) {
            cur = (int)((sFmap[c] >> (4 * cur)) & 15);
            sTagB[c] = cur;
        }
    }
    __syncthreads();

    // ---- chunk-parallel expansion -> predictions ----
    if (tid < 64) {
        const int c = tid;
        int cur = sTagB[c + 1];                 // tag at time 8c+8
        float* po = out + 1 + b * TLEN;
        for (int s = 8; s >= 1; --s) {
            const int t = c * 8 + s;
            if (t < TLEN) {
                int nxt = (int)((sBPp[t] >> (4 * cur)) & 15);   // tag at t-1
                po[t] = sMk[t - 1] ? (float)nxt : -100.f;
                cur = nxt;
            }
        }
    }
    if (tid == 0) {
        out[1 + b * TLEN] = -100.f;             // pred[0]
        wsLoss[b] = sDen - wsNum[b];
    }
}

// ---------------------------------------------------------------------------
// Kernel C: loss = sum_b (den_b - num_b)
// ---------------------------------------------------------------------------
__global__ __launch_bounds__(64) void loss_kernel(
    const double* __restrict__ wsLoss, float* __restrict__ out)
{
    double v = wsLoss[threadIdx.x];
    #pragma unroll
    for (int off = 32; off > 0; off >>= 1) v += __shfl_down(v, off);
    if (threadIdx.x == 0) out[0] = (float)v;
}

extern "C" void kernel_launch(void* const* d_in, const int* in_sizes, int n_in,
                              void* d_out, int out_size, void* d_ws, size_t ws_size,
                              hipStream_t stream)
{
    const float* hidden = (const float*)d_in[0];
    const float* W      = (const float*)d_in[1];
    const float* bvec   = (const float*)d_in[2];
    const float* trans  = (const float*)d_in[3];
    const int*   labels = (const int*)d_in[4];
    const int*   att    = (const int*)d_in[5];
    float* out = (float*)d_out;

    char* ws = (char*)d_ws;
    double* logitsD = (double*)(ws + WS_LOGD);
    float*  logitsF = (float*)(ws + WS_LOGF);
    double* wsVM    = (double*)(ws + WS_VM);
    float*  wsAM    = (float*)(ws + WS_AM);
    double* wsNum   = (double*)(ws + WS_NUM);
    double* wsLoss  = (double*)(ws + WS_LOSS);

    logits_kernel<<<512, 256, 0, stream>>>(hidden, W, bvec, logitsD, logitsF);
    crf1_kernel<<<BATCH, 576, 0, stream>>>(trans, labels, att, logitsD, logitsF,
                                           wsVM, wsAM, wsNum);
    crf2_kernel<<<BATCH, 128, 0, stream>>>(trans, labels, att, logitsD,
                                           wsVM, wsAM, wsNum, wsLoss, out);
    loss_kernel<<<1, 64, 0, stream>>>(wsLoss, out);
}

// Round 3
// 217.875 us; speedup vs baseline: 1.7507x; 1.2063x over previous
//
#include <hip/hip_runtime.h>

#define BATCH 64
#define TLEN  512
#define HDIM  768
#define LTAGS 9

// Workspace layout (bytes)
#define WS_LOGD 0                        // f64 [32768][9]   = 2359296
#define WS_LOGF 2359296                  // f32 [32768][9]   = 1179648
#define WS_VM   3538944                  // f64 [64][64][9][9] = 2654208
#define WS_AM   6193152                  // f32 [64][32][9][9] = 663552
#define WS_NUM  6856704                  // f64 [64]
#define WS_LOSS 6857216                  // f64 [64]

// ---------------------------------------------------------------------------
// Kernel A: logits = hidden @ W^T + b.  f32 dot4 segments accumulated in f64.
// ---------------------------------------------------------------------------
__global__ __launch_bounds__(256) void logits_kernel(
    const float* __restrict__ hidden, const float* __restrict__ W,
    const float* __restrict__ bvec, double* __restrict__ logitsD,
    float* __restrict__ logitsF)
{
    __shared__ float sW[LTAGS * HDIM];
    __shared__ float sb[LTAGS];
    const int tid = threadIdx.x;
    for (int i = tid; i < LTAGS * HDIM; i += 256) sW[i] = W[i];
    if (tid < LTAGS) sb[tid] = bvec[tid];
    __syncthreads();

    const int lane = tid & 63;
    const int wave = tid >> 6;
    const int sub  = lane & 7;
    const int rg   = lane >> 3;

    const int rowBase = blockIdx.x * 64 + wave * 16;
    const int r0 = rowBase + rg;
    const int r1 = rowBase + rg + 8;
    const float* h0p = hidden + (size_t)r0 * HDIM;
    const float* h1p = hidden + (size_t)r1 * HDIM;

    double acc0[LTAGS], acc1[LTAGS];
    #pragma unroll
    for (int l = 0; l < LTAGS; ++l) { acc0[l] = 0.0; acc1[l] = 0.0; }

    #pragma unroll 2
    for (int i = 0; i < 24; ++i) {
        const int off = i * 32 + sub * 4;
        const float4 h0 = *(const float4*)(h0p + off);
        const float4 h1 = *(const float4*)(h1p + off);
        #pragma unroll
        for (int l = 0; l < LTAGS; ++l) {
            const float4 w = *(const float4*)&sW[l * HDIM + off];
            float d0 = h0.x * w.x;
            d0 = fmaf(h0.y, w.y, d0); d0 = fmaf(h0.z, w.z, d0); d0 = fmaf(h0.w, w.w, d0);
            float d1 = h1.x * w.x;
            d1 = fmaf(h1.y, w.y, d1); d1 = fmaf(h1.z, w.z, d1); d1 = fmaf(h1.w, w.w, d1);
            acc0[l] += (double)d0;
            acc1[l] += (double)d1;
        }
    }
    #pragma unroll
    for (int l = 0; l < LTAGS; ++l) {
        double v0 = acc0[l], v1 = acc1[l];
        #pragma unroll
        for (int off = 4; off > 0; off >>= 1) {
            v0 += __shfl_down(v0, off);
            v1 += __shfl_down(v1, off);
        }
        acc0[l] = v0; acc1[l] = v1;
    }
    if (sub == 0) {
        #pragma unroll
        for (int l = 0; l < LTAGS; ++l) {
            double v0 = acc0[l] + (double)sb[l];
            double v1 = acc1[l] + (double)sb[l];
            logitsD[(size_t)r0 * LTAGS + l] = v0;
            logitsD[(size_t)r1 * LTAGS + l] = v1;
            logitsF[(size_t)r0 * LTAGS + l] = (float)v0;
            logitsF[(size_t)r1 * LTAGS + l] = (float)v1;
        }
    }
}

// ---------------------------------------------------------------------------
// Kernel B1 (chunk): 232 blocks x 256 threads.
//   blocks [0,144):   Viterbi chunk-matrix rows (b,c,i), f64 max-plus, 8 steps
//   blocks [144,216): alpha chunk-matrix rows (b,c,i), f32 log-plus, 16 steps
//   blocks [216,232): numerator, one wave per batch
// Per-thread op order identical to round-2 crf1 (bit-exact f64 path).
// ---------------------------------------------------------------------------
__global__ __launch_bounds__(256) void chunk_kernel(
    const float* __restrict__ trans, const int* __restrict__ labels,
    const int* __restrict__ att, const double* __restrict__ logitsD,
    const float* __restrict__ logitsF,
    double* __restrict__ wsVM, float* __restrict__ wsAM,
    double* __restrict__ wsNum)
{
    __shared__ double sT64[81];
    __shared__ float  sE32[81];
    const int tid = threadIdx.x;
    if (tid < 81) { float tv = trans[tid]; sT64[tid] = (double)tv; sE32[tid] = __expf(tv); }
    __syncthreads();

    const int blk = blockIdx.x;
    if (blk < 144) {
        // ---- Viterbi chunk rows ----
        const int gid = blk * 256 + tid;          // 0..36863
        const int b   = gid / 576;
        const int rem = gid - b * 576;
        const int c   = rem / 9;
        const int i   = rem - c * 9;

        double M[LTAGS];
        #pragma unroll
        for (int j = 0; j < LTAGS; ++j) M[j] = (i == j) ? 0.0 : -1e300;

        const double* lrow = logitsD + ((size_t)b * TLEN + (c * 8 + 1)) * LTAGS;
        const int* lab = labels + b * TLEN;
        const int* am  = att + b * TLEN;
        const int t0 = c * 8 + 1;

        double lg[LTAGS], lgN[LTAGS];
        #pragma unroll
        for (int j = 0; j < LTAGS; ++j) lg[j] = lrow[j];
        bool mk = (am[t0] != 0) && (lab[t0] != -100);

        for (int s = 0; s < 8; ++s) {
            bool mkN = false;
            const int tn = t0 + s + 1;
            if (s < 7 && tn <= TLEN - 1) {
                const double* ln = lrow + (s + 1) * LTAGS;
                #pragma unroll
                for (int j = 0; j < LTAGS; ++j) lgN[j] = ln[j];
                mkN = (am[tn] != 0) && (lab[tn] != -100);
            }
            double nw[LTAGS];
            #pragma unroll
            for (int j = 0; j < LTAGS; ++j) {
                double bst = M[0] + sT64[j];
                #pragma unroll
                for (int k = 1; k < LTAGS; ++k) {
                    double cnd = M[k] + sT64[k * LTAGS + j];
                    bst = fmax(bst, cnd);
                }
                nw[j] = bst + lg[j];
            }
            #pragma unroll
            for (int j = 0; j < LTAGS; ++j) { M[j] = mk ? nw[j] : M[j]; lg[j] = lgN[j]; }
            mk = mkN;
        }
        double* dst = wsVM + (((size_t)b * 64 + c) * LTAGS + i) * LTAGS;
        #pragma unroll
        for (int j = 0; j < LTAGS; ++j) dst[j] = M[j];
    } else if (blk < 216) {
        // ---- alpha chunk rows ----
        const int gid = (blk - 144) * 256 + tid;  // 0..18431
        const int b   = gid / 288;
        const int rem = gid - b * 288;
        const int c   = rem / 9;
        const int i   = rem - c * 9;

        float M[LTAGS];
        #pragma unroll
        for (int j = 0; j < LTAGS; ++j) M[j] = (i == j) ? 0.f : -1e30f;

        const float* lrow = logitsF + ((size_t)b * TLEN + (c * 16 + 1)) * LTAGS;
        const int* lab = labels + b * TLEN;
        const int* am  = att + b * TLEN;
        const int t0 = c * 16 + 1;

        float lg[LTAGS], lgN[LTAGS];
        #pragma unroll
        for (int j = 0; j < LTAGS; ++j) lg[j] = lrow[j];
        bool mk = (am[t0] != 0) && (lab[t0] != -100);

        for (int s = 0; s < 16; ++s) {
            bool mkN = false;
            const int tn = t0 + s + 1;
            if (s < 15 && tn <= TLEN - 1) {
                const float* ln = lrow + (s + 1) * LTAGS;
                #pragma unroll
                for (int j = 0; j < LTAGS; ++j) lgN[j] = ln[j];
                mkN = (am[tn] != 0) && (lab[tn] != -100);
            }
            float m = M[0];
            #pragma unroll
            for (int k = 1; k < LTAGS; ++k) m = fmaxf(m, M[k]);
            float P[LTAGS];
            #pragma unroll
            for (int k = 0; k < LTAGS; ++k) P[k] = __expf(M[k] - m);
            float nw[LTAGS];
            #pragma unroll
            for (int j = 0; j < LTAGS; ++j) {
                float sacc = P[0] * sE32[j];
                #pragma unroll
                for (int k = 1; k < LTAGS; ++k) sacc = fmaf(P[k], sE32[k * LTAGS + j], sacc);
                nw[j] = m + __logf(sacc) + lg[j];
            }
            #pragma unroll
            for (int j = 0; j < LTAGS; ++j) { M[j] = mk ? nw[j] : M[j]; lg[j] = lgN[j]; }
            mk = mkN;
        }
        float* dst = wsAM + (((size_t)b * 32 + c) * LTAGS + i) * LTAGS;
        #pragma unroll
        for (int j = 0; j < LTAGS; ++j) dst[j] = M[j];
    } else {
        // ---- numerator: one wave per batch ----
        const int bb   = (blk - 216) * 4 + (tid >> 6);
        const int lane = tid & 63;
        const int* lab = labels + bb * TLEN;
        const int* am  = att + bb * TLEN;
        const double* lrowb = logitsD + (size_t)bb * TLEN * LTAGS;
        double part = 0.0;
        #pragma unroll
        for (int k = 0; k < 8; ++k) {
            const int t = lane + k * 64;
            int lv = lab[t], av = am[t];
            bool mkc = (av != 0) && (lv != -100);
            int tg = (lv == -100) ? 0 : lv;
            if (mkc) part += lrowb[(size_t)t * LTAGS + tg];
            if (t < TLEN - 1) {
                int lv2 = lab[t + 1], av2 = am[t + 1];
                bool mk2 = (av2 != 0) && (lv2 != -100);
                int tg2 = (lv2 == -100) ? 0 : lv2;
                if (mk2) part += sT64[tg * LTAGS + tg2];
            }
        }
        #pragma unroll
        for (int off = 32; off > 0; off >>= 1) part += __shfl_down(part, off);
        if (lane == 0) wsNum[bb] = part;
    }
}

// ---------------------------------------------------------------------------
// Kernel B2 (crf2): per-batch block, 128 threads.  Chunk mats staged to LDS;
// wave0: serial max-plus boundary scan + replay + shfl-suffix backtrace
// wave1: serial log-plus boundary scan -> denominator
// ---------------------------------------------------------------------------
__global__ __launch_bounds__(128) void crf2_kernel(
    const float* __restrict__ trans, const int* __restrict__ labels,
    const int* __restrict__ att, const double* __restrict__ logitsD,
    const double* __restrict__ wsVM, const float* __restrict__ wsAM,
    const double* __restrict__ wsNum, double* __restrict__ wsLoss,
    float* __restrict__ out)
{
    __shared__ __align__(16) double sVM[64 * 81];     // 41472 B
    __shared__ __align__(16) float  sAM[32 * 81];     // 10368 B
    __shared__ double sVstart[65 * LTAGS];            // 4680 B
    __shared__ unsigned long long sBPp[513];          // 4104 B
    __shared__ int sTagB[65];
    __shared__ double sT64[81];
    __shared__ unsigned char sMk[513];
    __shared__ double sDen;
    __shared__ int sLast;

    const int b = blockIdx.x, tid = threadIdx.x;
    const int wave = tid >> 6, lane = tid & 63;
    const unsigned long long IDMAP = 0x876543210ull;

    // ---- stage chunk matrices + masks into LDS (coalesced) ----
    const double2* gVM = (const double2*)(wsVM + (size_t)b * 64 * 81);
    double2* sVM2 = (double2*)sVM;
    for (int i = tid; i < 2592; i += 128) sVM2[i] = gVM[i];
    const float4* gAM = (const float4*)(wsAM + (size_t)b * 32 * 81);
    float4* sAM4 = (float4*)sAM;
    for (int i = tid; i < 648; i += 128) sAM4[i] = gAM[i];

    const int* lab = labels + b * TLEN;
    const int* am  = att + b * TLEN;
    for (int t = tid; t < TLEN; t += 128) {
        int lv = lab[t], av = am[t];
        sMk[t] = (av != 0 && lv != -100) ? 1 : 0;
    }
    if (tid == 0) sMk[TLEN] = 0;
    if (tid < 81) sT64[tid] = (double)trans[tid];
    __syncthreads();

    if (wave == 0) {
        // ---- Viterbi boundary scan over 64 chunk matrices (LDS) ----
        const int j = (lane < LTAGS) ? lane : (LTAGS - 1);
        double v = logitsD[(size_t)b * TLEN * LTAGS + j];
        double Mc[LTAGS], Mn[LTAGS];
        #pragma unroll
        for (int i = 0; i < LTAGS; ++i) Mc[i] = sVM[i * LTAGS + j];
        for (int c = 0; c < 64; ++c) {
            if (c < 63) {
                #pragma unroll
                for (int i = 0; i < LTAGS; ++i) Mn[i] = sVM[(c + 1) * 81 + i * LTAGS + j];
            }
            if (lane < LTAGS) sVstart[c * LTAGS + j] = v;
            double g[LTAGS];
            #pragma unroll
            for (int i = 0; i < LTAGS; ++i) g[i] = __shfl(v, i);
            double bst = g[0] + Mc[0];
            #pragma unroll
            for (int i = 1; i < LTAGS; ++i) bst = fmax(bst, g[i] + Mc[i]);
            v = bst;
            if (c < 63) {
                #pragma unroll
                for (int i = 0; i < LTAGS; ++i) Mc[i] = Mn[i];
            }
        }
        if (lane < LTAGS) sVstart[64 * LTAGS + j] = v;
        double g[LTAGS];
        #pragma unroll
        for (int i = 0; i < LTAGS; ++i) g[i] = __shfl(v, i);
        if (lane == 0) {
            int bi = 0; double bv = g[0];
            #pragma unroll
            for (int i = 1; i < LTAGS; ++i) if (g[i] > bv) { bv = g[i]; bi = i; }
            sLast = bi;
        }
    } else {
        // ---- alpha boundary scan over 32 chunk matrices (LDS) ----
        const int j = (lane < LTAGS) ? lane : (LTAGS - 1);
        float v = (float)logitsD[(size_t)b * TLEN * LTAGS + j];
        float Mc[LTAGS], Mn[LTAGS];
        #pragma unroll
        for (int i = 0; i < LTAGS; ++i) Mc[i] = sAM[i * LTAGS + j];
        for (int c = 0; c < 32; ++c) {
            if (c < 31) {
                #pragma unroll
                for (int i = 0; i < LTAGS; ++i) Mn[i] = sAM[(c + 1) * 81 + i * LTAGS + j];
            }
            float g[LTAGS];
            #pragma unroll
            for (int i = 0; i < LTAGS; ++i) g[i] = __shfl(v, i);
            float a[LTAGS];
            #pragma unroll
            for (int i = 0; i < LTAGS; ++i) a[i] = g[i] + Mc[i];
            float m = a[0];
            #pragma unroll
            for (int i = 1; i < LTAGS; ++i) m = fmaxf(m, a[i]);
            float sacc = 0.f;
            #pragma unroll
            for (int i = 0; i < LTAGS; ++i) sacc += __expf(a[i] - m);
            v = m + __logf(sacc);
            if (c < 31) {
                #pragma unroll
                for (int i = 0; i < LTAGS; ++i) Mc[i] = Mn[i];
            }
        }
        float g[LTAGS];
        #pragma unroll
        for (int i = 0; i < LTAGS; ++i) g[i] = __shfl(v, i);
        if (lane == 0) {
            float m = g[0];
            #pragma unroll
            for (int i = 1; i < LTAGS; ++i) m = fmaxf(m, g[i]);
            float sacc = 0.f;
            #pragma unroll
            for (int i = 0; i < LTAGS; ++i) sacc += __expf(g[i] - m);
            sDen = (double)(m + __logf(sacc));
        }
    }
    __syncthreads();

    // ---- replay: backpointers + per-chunk composed maps (threads 0..63) ----
    unsigned long long S = IDMAP;
    if (tid < 64) {
        const int c = tid;
        double v[LTAGS];
        #pragma unroll
        for (int j = 0; j < LTAGS; ++j) v[j] = sVstart[c * LTAGS + j];
        const double* lrow = logitsD + ((size_t)b * TLEN + (c * 8 + 1)) * LTAGS;
        double lg[LTAGS], lgN[LTAGS];
        #pragma unroll
        for (int j = 0; j < LTAGS; ++j) lg[j] = lrow[j];

        for (int s = 0; s < 8; ++s) {
            const int t = c * 8 + 1 + s;
            if (s < 7 && t + 1 <= TLEN - 1) {
                const double* ln = lrow + (s + 1) * LTAGS;
                #pragma unroll
                for (int j = 0; j < LTAGS; ++j) lgN[j] = ln[j];
            }
            const bool mk = (sMk[t] != 0);
            unsigned long long pk = 0;
            double nv[LTAGS];
            #pragma unroll
            for (int j = 0; j < LTAGS; ++j) {
                double bst = v[0] + sT64[j];
                int bi = 0;
                #pragma unroll
                for (int k = 1; k < LTAGS; ++k) {
                    double cnd = v[k] + sT64[k * LTAGS + j];
                    bool gt = cnd > bst;
                    bst = gt ? cnd : bst;
                    bi  = gt ? k : bi;
                }
                nv[j] = bst + lg[j];
                pk |= ((unsigned long long)bi) << (4 * j);
            }
            pk = mk ? pk : IDMAP;
            sBPp[t] = pk;
            #pragma unroll
            for (int j = 0; j < LTAGS; ++j) { v[j] = mk ? nv[j] : v[j]; lg[j] = lgN[j]; }
        }
        // compose chunk backtrace map
        unsigned long long G = IDMAP;
        for (int s = 7; s >= 0; --s) {
            const unsigned long long bp = sBPp[c * 8 + 1 + s];
            unsigned long long ng = 0;
            #pragma unroll
            for (int j = 0; j < LTAGS; ++j) {
                int gj = (int)((G >> (4 * j)) & 15);
                int f  = (int)((bp >> (4 * gj)) & 15);
                ng |= ((unsigned long long)f) << (4 * j);
            }
            G = ng;
        }
        S = G;
    }

    // ---- suffix composition scan via shfl: S_c = F_c o ... o F_63 ----
    #pragma unroll
    for (int d = 1; d < 64; d <<= 1) {
        unsigned long long Sn = __shfl_down(S, d);
        if (wave == 0 && lane + d < 64) {
            unsigned long long R = 0;
            #pragma unroll
            for (int x = 0; x < LTAGS; ++x) {
                int y = (int)((Sn >> (4 * x)) & 15);
                int z = (int)((S >> (4 * y)) & 15);
                R |= ((unsigned long long)z) << (4 * x);
            }
            S = R;
        }
    }
    if (tid < 64) {
        const int lt = sLast;
        sTagB[tid] = (int)((S >> (4 * lt)) & 15);
        if (tid == 0) sTagB[64] = lt;
    }
    __syncthreads();

    // ---- chunk-parallel expansion -> predictions ----
    if (tid < 64) {
        const int c = tid;
        int cur = sTagB[c + 1];
        float* po = out + 1 + b * TLEN;
        for (int s = 8; s >= 1; --s) {
            const int t = c * 8 + s;
            if (t < TLEN) {
                int nxt = (int)((sBPp[t] >> (4 * cur)) & 15);
                po[t] = sMk[t - 1] ? (float)nxt : -100.f;
                cur = nxt;
            }
        }
    }
    if (tid == 0) {
        out[1 + b * TLEN] = -100.f;
        wsLoss[b] = sDen - wsNum[b];
    }
}

// ---------------------------------------------------------------------------
// Kernel C: loss = sum_b (den_b - num_b)
// ---------------------------------------------------------------------------
__global__ __launch_bounds__(64) void loss_kernel(
    const double* __restrict__ wsLoss, float* __restrict__ out)
{
    double v = wsLoss[threadIdx.x];
    #pragma unroll
    for (int off = 32; off > 0; off >>= 1) v += __shfl_down(v, off);
    if (threadIdx.x == 0) out[0] = (float)v;
}

extern "C" void kernel_launch(void* const* d_in, const int* in_sizes, int n_in,
                              void* d_out, int out_size, void* d_ws, size_t ws_size,
                              hipStream_t stream)
{
    const float* hidden = (const float*)d_in[0];
    const float* W      = (const float*)d_in[1];
    const float* bvec   = (const float*)d_in[2];
    const float* trans  = (const float*)d_in[3];
    const int*   labels = (const int*)d_in[4];
    const int*   att    = (const int*)d_in[5];
    float* out = (float*)d_out;

    char* ws = (char*)d_ws;
    double* logitsD = (double*)(ws + WS_LOGD);
    float*  logitsF = (float*)(ws + WS_LOGF);
    double* wsVM    = (double*)(ws + WS_VM);
    float*  wsAM    = (float*)(ws + WS_AM);
    double* wsNum   = (double*)(ws + WS_NUM);
    double* wsLoss  = (double*)(ws + WS_LOSS);

    logits_kernel<<<512, 256, 0, stream>>>(hidden, W, bvec, logitsD, logitsF);
    chunk_kernel<<<232, 256, 0, stream>>>(trans, labels, att, logitsD, logitsF,
                                          wsVM, wsAM, wsNum);
    crf2_kernel<<<BATCH, 128, 0, stream>>>(trans, labels, att, logitsD,
                                           wsVM, wsAM, wsNum, wsLoss, out);
    loss_kernel<<<1, 64, 0, stream>>>(wsLoss, out);
}